// Round 1
// baseline (36.671 us; speedup 1.0000x reference)
//
#include <hip/hip_runtime.h>

struct M3 { float a[9]; };
struct V3 { float x, y, z; };

__device__ __forceinline__ M3 rot6d(const float* __restrict__ r) {
    float x0 = r[0], x1 = r[1], x2 = r[2];
    float y0 = r[3], y1 = r[4], y2 = r[5];
    float inx = 1.0f / fmaxf(sqrtf(x0*x0 + x1*x1 + x2*x2), 1e-8f);
    x0 *= inx; x1 *= inx; x2 *= inx;
    // z = normalize(cross(x, y_raw))
    float z0 = x1*y2 - x2*y1;
    float z1 = x2*y0 - x0*y2;
    float z2 = x0*y1 - x1*y0;
    float inz = 1.0f / fmaxf(sqrtf(z0*z0 + z1*z1 + z2*z2), 1e-8f);
    z0 *= inz; z1 *= inz; z2 *= inz;
    // y = cross(z, x)
    float w0 = z1*x2 - z2*x1;
    float w1 = z2*x0 - z0*x2;
    float w2 = z0*x1 - z1*x0;
    M3 R;
    // columns are x, y, z; row-major a[3*row+col]
    R.a[0] = x0; R.a[1] = w0; R.a[2] = z0;
    R.a[3] = x1; R.a[4] = w1; R.a[5] = z1;
    R.a[6] = x2; R.a[7] = w2; R.a[8] = z2;
    return R;
}

__device__ __forceinline__ M3 m3mul(const M3& A, const M3& B) {
    M3 C;
#pragma unroll
    for (int r = 0; r < 3; ++r) {
#pragma unroll
        for (int c = 0; c < 3; ++c) {
            C.a[3*r + c] = A.a[3*r + 0] * B.a[0 + c]
                         + A.a[3*r + 1] * B.a[3 + c]
                         + A.a[3*r + 2] * B.a[6 + c];
        }
    }
    return C;
}

// pos[j] = pos[p] + s * column<axis>(Rw[p])
__device__ __forceinline__ V3 step(const M3& P, V3 pp, int axis, float s) {
    V3 q;
    q.x = pp.x + s * P.a[0 + axis];
    q.y = pp.y + s * P.a[3 + axis];
    q.z = pp.z + s * P.a[6 + axis];
    return q;
}

__device__ __forceinline__ void store3(float* __restrict__ o, int j, V3 q) {
    o[3*j + 0] = q.x;
    o[3*j + 1] = q.y;
    o[3*j + 2] = q.z;
}

__global__ __launch_bounds__(256) void PoseDecoder_kernel(
    const float* __restrict__ rot,    // [BL,17,6]
    const float* __restrict__ bones,  // [B,16]
    const float* __restrict__ root,   // [BL,3]
    float* __restrict__ out,          // [BL,17,3]
    int BL, int L)
{
    int i = blockIdx.x * 256 + threadIdx.x;
    if (i >= BL) return;
    int b = i / L;

    const float* __restrict__ r6 = rot + (size_t)i * 102;
    float* __restrict__ o = out + (size_t)i * 51;
    const float* __restrict__ bl = bones + (size_t)b * 16;

    float len[16];
#pragma unroll
    for (int k = 0; k < 16; ++k) len[k] = bl[k];

    // joint 0
    M3 W0 = rot6d(r6 + 0);
    V3 q0; q0.x = root[3*(size_t)i + 0]; q0.y = root[3*(size_t)i + 1]; q0.z = root[3*(size_t)i + 2];
    store3(o, 0, q0);

    // chain 0 -> 1 -> 2 -> 3
    M3 W1 = m3mul(W0, rot6d(r6 + 1*6));  V3 q1 = step(W0, q0, 0, -len[0]);  store3(o, 1, q1);
    M3 W2 = m3mul(W1, rot6d(r6 + 2*6));  V3 q2 = step(W1, q1, 1, -len[1]);  store3(o, 2, q2);
    /* leaf 3 */                         V3 q3 = step(W2, q2, 1, -len[2]);  store3(o, 3, q3);

    // chain 0 -> 4 -> 5 -> 6
    M3 W4 = m3mul(W0, rot6d(r6 + 4*6));  V3 q4 = step(W0, q0, 0,  len[3]);  store3(o, 4, q4);
    M3 W5 = m3mul(W4, rot6d(r6 + 5*6));  V3 q5 = step(W4, q4, 1, -len[4]);  store3(o, 5, q5);
    /* leaf 6 */                         V3 q6 = step(W5, q5, 1, -len[5]);  store3(o, 6, q6);

    // chain 0 -> 7 -> 8
    M3 W7 = m3mul(W0, rot6d(r6 + 7*6));  V3 q7 = step(W0, q0, 1,  len[6]);  store3(o, 7, q7);
    M3 W8 = m3mul(W7, rot6d(r6 + 8*6));  V3 q8 = step(W7, q7, 1,  len[7]);  store3(o, 8, q8);

    // chain 8 -> 9 -> 10
    M3 W9 = m3mul(W8, rot6d(r6 + 9*6));  V3 q9 = step(W8, q8, 1,  len[8]);  store3(o, 9, q9);
    /* leaf 10 */                        V3 q10 = step(W9, q9, 1, len[9]);  store3(o, 10, q10);

    // chain 8 -> 11 -> 12 -> 13
    M3 W11 = m3mul(W8, rot6d(r6 + 11*6)); V3 q11 = step(W8,  q8,  0, len[10]); store3(o, 11, q11);
    M3 W12 = m3mul(W11, rot6d(r6 + 12*6)); V3 q12 = step(W11, q11, 0, len[11]); store3(o, 12, q12);
    /* leaf 13 */                          V3 q13 = step(W12, q12, 0, len[12]); store3(o, 13, q13);

    // chain 8 -> 14 -> 15 -> 16
    M3 W14 = m3mul(W8, rot6d(r6 + 14*6)); V3 q14 = step(W8,  q8,  0, -len[13]); store3(o, 14, q14);
    M3 W15 = m3mul(W14, rot6d(r6 + 15*6)); V3 q15 = step(W14, q14, 0, -len[14]); store3(o, 15, q15);
    /* leaf 16 */                          V3 q16 = step(W15, q15, 0, -len[15]); store3(o, 16, q16);
}

extern "C" void kernel_launch(void* const* d_in, const int* in_sizes, int n_in,
                              void* d_out, int out_size, void* d_ws, size_t ws_size,
                              hipStream_t stream) {
    const float* rot   = (const float*)d_in[0];
    const float* bones = (const float*)d_in[1];
    const float* root  = (const float*)d_in[2];
    float* out = (float*)d_out;

    int BL = in_sizes[0] / 102;     // 17 joints * 6
    int B  = in_sizes[1] / 16;      // 16 bones
    int L  = BL / B;

    int grid = (BL + 255) / 256;
    PoseDecoder_kernel<<<grid, 256, 0, stream>>>(rot, bones, root, out, BL, L);
}

// Round 2
// 32.802 us; speedup vs baseline: 1.1180x; 1.1180x over previous
//
#include <hip/hip_runtime.h>

#define SPB 128   // samples per block
#define TPB 128   // threads per block

struct M3 { float a[9]; };
struct V3 { float x, y, z; };

__device__ __forceinline__ M3 rot6d(const float* __restrict__ r) {
    float x0 = r[0], x1 = r[1], x2 = r[2];
    float y0 = r[3], y1 = r[4], y2 = r[5];
    float inx = 1.0f / fmaxf(sqrtf(x0*x0 + x1*x1 + x2*x2), 1e-8f);
    x0 *= inx; x1 *= inx; x2 *= inx;
    float z0 = x1*y2 - x2*y1;
    float z1 = x2*y0 - x0*y2;
    float z2 = x0*y1 - x1*y0;
    float inz = 1.0f / fmaxf(sqrtf(z0*z0 + z1*z1 + z2*z2), 1e-8f);
    z0 *= inz; z1 *= inz; z2 *= inz;
    float w0 = z1*x2 - z2*x1;
    float w1 = z2*x0 - z0*x2;
    float w2 = z0*x1 - z1*x0;
    M3 R;
    R.a[0] = x0; R.a[1] = w0; R.a[2] = z0;
    R.a[3] = x1; R.a[4] = w1; R.a[5] = z1;
    R.a[6] = x2; R.a[7] = w2; R.a[8] = z2;
    return R;
}

__device__ __forceinline__ M3 m3mul(const M3& A, const M3& B) {
    M3 C;
#pragma unroll
    for (int r = 0; r < 3; ++r)
#pragma unroll
        for (int c = 0; c < 3; ++c)
            C.a[3*r + c] = A.a[3*r + 0] * B.a[0 + c]
                         + A.a[3*r + 1] * B.a[3 + c]
                         + A.a[3*r + 2] * B.a[6 + c];
    return C;
}

__device__ __forceinline__ V3 step(const M3& P, V3 pp, int axis, float s) {
    V3 q;
    q.x = pp.x + s * P.a[0 + axis];
    q.y = pp.y + s * P.a[3 + axis];
    q.z = pp.z + s * P.a[6 + axis];
    return q;
}

__global__ __launch_bounds__(TPB) void PoseDecoder_kernel(
    const float* __restrict__ rot,    // [BL,17,6]
    const float* __restrict__ bones,  // [B,16]
    const float* __restrict__ root,   // [BL,3]
    float* __restrict__ out,          // [BL,17,3]
    int BL, int L)
{
    __shared__ __align__(16) float smem[SPB * 102 + SPB * 3];
    float* s_in   = smem;               // [SPB][102] linear image of rot block
    float* s_root = smem + SPB * 102;   // [SPB][3]

    const int base = blockIdx.x * SPB;
    const int t = threadIdx.x;
    int nvalid = BL - base; if (nvalid > SPB) nvalid = SPB;

    // ---- Phase 1: coalesced global -> LDS staging ----
    {
        const int nf = nvalid * 102;
        const int nf4 = nf >> 2;                       // 128*102/4 = 3264
        const float4* __restrict__ g4 = (const float4*)(rot + (size_t)base * 102);
        float4* l4 = (float4*)s_in;
        for (int v = t; v < nf4; v += TPB) l4[v] = g4[v];
        for (int e = (nf4 << 2) + t; e < nf; e += TPB)
            s_in[e] = rot[(size_t)base * 102 + e];
        const int nr = nvalid * 3;
        const float* __restrict__ gr = root + (size_t)base * 3;
        for (int e = t; e < nr; e += TPB) s_root[e] = gr[e];
    }
    __syncthreads();

    // ---- Phase 2: per-thread FK out of LDS, results in registers ----
    float res[51];
    if (t < nvalid) {
        const float* r6 = s_in + t * 102;
        const int gs = base + t;
        const float* __restrict__ bl = bones + (size_t)(gs / L) * 16;
        float len[16];
#pragma unroll
        for (int k = 0; k < 16; ++k) len[k] = bl[k];

        V3 q0; q0.x = s_root[t*3 + 0]; q0.y = s_root[t*3 + 1]; q0.z = s_root[t*3 + 2];
        M3 W0 = rot6d(r6 + 0);
        res[0] = q0.x; res[1] = q0.y; res[2] = q0.z;

        // chain 0 -> 1 -> 2 -> 3
        M3 W1 = m3mul(W0, rot6d(r6 + 1*6));  V3 q1 = step(W0, q0, 0, -len[0]);
        M3 W2 = m3mul(W1, rot6d(r6 + 2*6));  V3 q2 = step(W1, q1, 1, -len[1]);
        /* leaf 3 */                         V3 q3 = step(W2, q2, 1, -len[2]);
        res[3]=q1.x; res[4]=q1.y; res[5]=q1.z;
        res[6]=q2.x; res[7]=q2.y; res[8]=q2.z;
        res[9]=q3.x; res[10]=q3.y; res[11]=q3.z;

        // chain 0 -> 4 -> 5 -> 6
        M3 W4 = m3mul(W0, rot6d(r6 + 4*6));  V3 q4 = step(W0, q0, 0,  len[3]);
        M3 W5 = m3mul(W4, rot6d(r6 + 5*6));  V3 q5 = step(W4, q4, 1, -len[4]);
        /* leaf 6 */                         V3 q6 = step(W5, q5, 1, -len[5]);
        res[12]=q4.x; res[13]=q4.y; res[14]=q4.z;
        res[15]=q5.x; res[16]=q5.y; res[17]=q5.z;
        res[18]=q6.x; res[19]=q6.y; res[20]=q6.z;

        // chain 0 -> 7 -> 8
        M3 W7 = m3mul(W0, rot6d(r6 + 7*6));  V3 q7 = step(W0, q0, 1,  len[6]);
        M3 W8 = m3mul(W7, rot6d(r6 + 8*6));  V3 q8 = step(W7, q7, 1,  len[7]);
        res[21]=q7.x; res[22]=q7.y; res[23]=q7.z;
        res[24]=q8.x; res[25]=q8.y; res[26]=q8.z;

        // chain 8 -> 9 -> 10
        M3 W9 = m3mul(W8, rot6d(r6 + 9*6));  V3 q9 = step(W8, q8, 1,  len[8]);
        /* leaf 10 */                        V3 q10 = step(W9, q9, 1, len[9]);
        res[27]=q9.x; res[28]=q9.y; res[29]=q9.z;
        res[30]=q10.x; res[31]=q10.y; res[32]=q10.z;

        // chain 8 -> 11 -> 12 -> 13
        M3 W11 = m3mul(W8,  rot6d(r6 + 11*6)); V3 q11 = step(W8,  q8,  0, len[10]);
        M3 W12 = m3mul(W11, rot6d(r6 + 12*6)); V3 q12 = step(W11, q11, 0, len[11]);
        /* leaf 13 */                          V3 q13 = step(W12, q12, 0, len[12]);
        res[33]=q11.x; res[34]=q11.y; res[35]=q11.z;
        res[36]=q12.x; res[37]=q12.y; res[38]=q12.z;
        res[39]=q13.x; res[40]=q13.y; res[41]=q13.z;

        // chain 8 -> 14 -> 15 -> 16
        M3 W14 = m3mul(W8,  rot6d(r6 + 14*6)); V3 q14 = step(W8,  q8,  0, -len[13]);
        M3 W15 = m3mul(W14, rot6d(r6 + 15*6)); V3 q15 = step(W14, q14, 0, -len[14]);
        /* leaf 16 */                          V3 q16 = step(W15, q15, 0, -len[15]);
        res[42]=q14.x; res[43]=q14.y; res[44]=q14.z;
        res[45]=q15.x; res[46]=q15.y; res[47]=q15.z;
        res[48]=q16.x; res[49]=q16.y; res[50]=q16.z;
    }
    __syncthreads();   // all compute-phase LDS reads done before overlay write

    // ---- Phase 3: results -> LDS (overlay), linear [s][51] ----
    float* s_out = smem;
    if (t < nvalid) {
#pragma unroll
        for (int m = 0; m < 51; ++m) s_out[t * 51 + m] = res[m];
    }
    __syncthreads();

    // ---- Phase 4: coalesced LDS -> global store ----
    {
        const int nf = nvalid * 51;
        const int nf4 = nf >> 2;                       // 128*51/4 = 1632
        float4* __restrict__ o4 = (float4*)(out + (size_t)base * 51);
        const float4* l4 = (const float4*)s_out;
        for (int v = t; v < nf4; v += TPB) o4[v] = l4[v];
        for (int e = (nf4 << 2) + t; e < nf; e += TPB)
            out[(size_t)base * 51 + e] = s_out[e];
    }
}

extern "C" void kernel_launch(void* const* d_in, const int* in_sizes, int n_in,
                              void* d_out, int out_size, void* d_ws, size_t ws_size,
                              hipStream_t stream) {
    const float* rot   = (const float*)d_in[0];
    const float* bones = (const float*)d_in[1];
    const float* root  = (const float*)d_in[2];
    float* out = (float*)d_out;

    int BL = in_sizes[0] / 102;     // 17 joints * 6
    int B  = in_sizes[1] / 16;      // 16 bones
    int L  = BL / B;

    int grid = (BL + SPB - 1) / SPB;
    PoseDecoder_kernel<<<grid, TPB, 0, stream>>>(rot, bones, root, out, BL, L);
}

// Round 3
// 30.613 us; speedup vs baseline: 1.1979x; 1.0715x over previous
//
#include <hip/hip_runtime.h>

#define TPB 64          // one wave per block — wave-synchronous, no barriers
#define STRIDE_IN 102   // dwords per sample in LDS (input image)

struct M3 { float a[9]; };
struct V3 { float x, y, z; };

// Intra-wave LDS fence: wave lanes are lockstep and the per-wave DS pipe is
// in-order, so all we need is (a) stop compiler reordering across the phase
// boundary, (b) drain lgkm so nothing is half-issued.
__device__ __forceinline__ void wave_fence() {
    asm volatile("s_waitcnt lgkmcnt(0)" ::: "memory");
    __builtin_amdgcn_wave_barrier();
}

__device__ __forceinline__ M3 rot6d(const float* r) {
    float x0 = r[0], x1 = r[1], x2 = r[2];
    float y0 = r[3], y1 = r[4], y2 = r[5];
    float inx = rsqrtf(fmaxf(x0*x0 + x1*x1 + x2*x2, 1e-16f));
    x0 *= inx; x1 *= inx; x2 *= inx;
    float z0 = x1*y2 - x2*y1;
    float z1 = x2*y0 - x0*y2;
    float z2 = x0*y1 - x1*y0;
    float inz = rsqrtf(fmaxf(z0*z0 + z1*z1 + z2*z2, 1e-16f));
    z0 *= inz; z1 *= inz; z2 *= inz;
    float w0 = z1*x2 - z2*x1;
    float w1 = z2*x0 - z0*x2;
    float w2 = z0*x1 - z1*x0;
    M3 R;
    R.a[0] = x0; R.a[1] = w0; R.a[2] = z0;
    R.a[3] = x1; R.a[4] = w1; R.a[5] = z1;
    R.a[6] = x2; R.a[7] = w2; R.a[8] = z2;
    return R;
}

__device__ __forceinline__ M3 m3mul(const M3& A, const M3& B) {
    M3 C;
#pragma unroll
    for (int r = 0; r < 3; ++r)
#pragma unroll
        for (int c = 0; c < 3; ++c)
            C.a[3*r + c] = A.a[3*r + 0] * B.a[0 + c]
                         + A.a[3*r + 1] * B.a[3 + c]
                         + A.a[3*r + 2] * B.a[6 + c];
    return C;
}

__device__ __forceinline__ V3 step(const M3& P, V3 pp, int axis, float s) {
    V3 q;
    q.x = pp.x + s * P.a[0 + axis];
    q.y = pp.y + s * P.a[3 + axis];
    q.z = pp.z + s * P.a[6 + axis];
    return q;
}

__global__ __launch_bounds__(TPB) void PoseDecoder_kernel(
    const float* __restrict__ rot,    // [BL,17,6]
    const float* __restrict__ bones,  // [B,16]
    const float* __restrict__ root,   // [BL,3]
    float* __restrict__ out,          // [BL,17,3]
    int BL, int L)
{
    __shared__ __align__(16) float s_buf[TPB * STRIDE_IN];  // 26112 B -> 6 blocks/CU
    const int t = threadIdx.x;
    const int base = blockIdx.x * TPB;
    int nvalid = BL - base; if (nvalid > TPB) nvalid = TPB;

    // ---- Phase 1: coalesced global -> LDS (wave-local, float4) ----
    {
        const int nf = nvalid * 102;
        const int nf4 = nf >> 2;                           // 64*102/4 = 1632
        const float4* g4 = (const float4*)(rot + (size_t)base * 102);  // base*408 B, 16B-aligned (64*408 % 16 == 0)
        float4* l4 = (float4*)s_buf;
        for (int v = t; v < nf4; v += TPB) l4[v] = g4[v];
        for (int e = (nf4 << 2) + t; e < nf; e += TPB)
            s_buf[e] = rot[(size_t)base * 102 + e];
    }
    wave_fence();

    // ---- Phase 2: per-lane FK out of LDS ----
    float res[51];
    if (t < nvalid) {
        const float* r6 = s_buf + t * STRIDE_IN;
        const int gs = base + t;

        // bones index is wave-uniform when the whole block falls in one b
        const int b_first = base / L;
        const int b_last  = (base + TPB - 1) / L;
        float len[16];
        if (b_first == b_last) {
            const float* bl = bones + (size_t)b_first * 16;   // scalar loads
#pragma unroll
            for (int k = 0; k < 16; ++k) len[k] = bl[k];
        } else {
            const float* bl = bones + (size_t)(gs / L) * 16;
#pragma unroll
            for (int k = 0; k < 16; ++k) len[k] = bl[k];
        }

        V3 q0; q0.x = root[3*(size_t)gs + 0]; q0.y = root[3*(size_t)gs + 1]; q0.z = root[3*(size_t)gs + 2];
        M3 W0 = rot6d(r6 + 0);
        res[0] = q0.x; res[1] = q0.y; res[2] = q0.z;

        // chain 0 -> 1 -> 2 -> 3
        M3 W1 = m3mul(W0, rot6d(r6 + 1*6));  V3 q1 = step(W0, q0, 0, -len[0]);
        M3 W2 = m3mul(W1, rot6d(r6 + 2*6));  V3 q2 = step(W1, q1, 1, -len[1]);
        /* leaf 3 */                         V3 q3 = step(W2, q2, 1, -len[2]);
        res[3]=q1.x; res[4]=q1.y; res[5]=q1.z;
        res[6]=q2.x; res[7]=q2.y; res[8]=q2.z;
        res[9]=q3.x; res[10]=q3.y; res[11]=q3.z;

        // chain 0 -> 4 -> 5 -> 6
        M3 W4 = m3mul(W0, rot6d(r6 + 4*6));  V3 q4 = step(W0, q0, 0,  len[3]);
        M3 W5 = m3mul(W4, rot6d(r6 + 5*6));  V3 q5 = step(W4, q4, 1, -len[4]);
        /* leaf 6 */                         V3 q6 = step(W5, q5, 1, -len[5]);
        res[12]=q4.x; res[13]=q4.y; res[14]=q4.z;
        res[15]=q5.x; res[16]=q5.y; res[17]=q5.z;
        res[18]=q6.x; res[19]=q6.y; res[20]=q6.z;

        // chain 0 -> 7 -> 8
        M3 W7 = m3mul(W0, rot6d(r6 + 7*6));  V3 q7 = step(W0, q0, 1,  len[6]);
        M3 W8 = m3mul(W7, rot6d(r6 + 8*6));  V3 q8 = step(W7, q7, 1,  len[7]);
        res[21]=q7.x; res[22]=q7.y; res[23]=q7.z;
        res[24]=q8.x; res[25]=q8.y; res[26]=q8.z;

        // chain 8 -> 9 -> 10
        M3 W9 = m3mul(W8, rot6d(r6 + 9*6));  V3 q9 = step(W8, q8, 1,  len[8]);
        /* leaf 10 */                        V3 q10 = step(W9, q9, 1, len[9]);
        res[27]=q9.x; res[28]=q9.y; res[29]=q9.z;
        res[30]=q10.x; res[31]=q10.y; res[32]=q10.z;

        // chain 8 -> 11 -> 12 -> 13
        M3 W11 = m3mul(W8,  rot6d(r6 + 11*6)); V3 q11 = step(W8,  q8,  0, len[10]);
        M3 W12 = m3mul(W11, rot6d(r6 + 12*6)); V3 q12 = step(W11, q11, 0, len[11]);
        /* leaf 13 */                          V3 q13 = step(W12, q12, 0, len[12]);
        res[33]=q11.x; res[34]=q11.y; res[35]=q11.z;
        res[36]=q12.x; res[37]=q12.y; res[38]=q12.z;
        res[39]=q13.x; res[40]=q13.y; res[41]=q13.z;

        // chain 8 -> 14 -> 15 -> 16
        M3 W14 = m3mul(W8,  rot6d(r6 + 14*6)); V3 q14 = step(W8,  q8,  0, -len[13]);
        M3 W15 = m3mul(W14, rot6d(r6 + 15*6)); V3 q15 = step(W14, q14, 0, -len[14]);
        /* leaf 16 */                          V3 q16 = step(W15, q15, 0, -len[15]);
        res[42]=q14.x; res[43]=q14.y; res[44]=q14.z;
        res[45]=q15.x; res[46]=q15.y; res[47]=q15.z;
        res[48]=q16.x; res[49]=q16.y; res[50]=q16.z;
    }
    wave_fence();   // all input LDS reads retired before the overlay write

    // ---- Phase 3: results -> LDS overlay (stride 51, 2-way banks = free) ----
    if (t < nvalid) {
        float* so = s_buf + t * 51;
#pragma unroll
        for (int m = 0; m < 51; ++m) so[m] = res[m];
    }
    wave_fence();

    // ---- Phase 4: coalesced LDS -> global (float4) ----
    {
        const int nf = nvalid * 51;
        const int nf4 = nf >> 2;                           // 64*51/4 = 816
        float4* o4 = (float4*)(out + (size_t)base * 51);   // base*204 B, 16B-aligned
        const float4* l4 = (const float4*)s_buf;
        for (int v = t; v < nf4; v += TPB) o4[v] = l4[v];
        for (int e = (nf4 << 2) + t; e < nf; e += TPB)
            out[(size_t)base * 51 + e] = s_buf[e];
    }
}

extern "C" void kernel_launch(void* const* d_in, const int* in_sizes, int n_in,
                              void* d_out, int out_size, void* d_ws, size_t ws_size,
                              hipStream_t stream) {
    const float* rot   = (const float*)d_in[0];
    const float* bones = (const float*)d_in[1];
    const float* root  = (const float*)d_in[2];
    float* out = (float*)d_out;

    int BL = in_sizes[0] / 102;     // 17 joints * 6
    int B  = in_sizes[1] / 16;      // 16 bones
    int L  = BL / B;

    int grid = (BL + TPB - 1) / TPB;
    PoseDecoder_kernel<<<grid, TPB, 0, stream>>>(rot, bones, root, out, BL, L);
}

// Round 4
// 20.662 us; speedup vs baseline: 1.7748x; 1.4816x over previous
//
#include <hip/hip_runtime.h>

#define TPB 64          // one wave per block — wave-synchronous, no barriers
#define STRIDE_IN 102   // dwords per sample in LDS (input image)

typedef const __attribute__((address_space(1))) void g_void;
typedef __attribute__((address_space(3))) void lds_void;

struct M3 { float a[9]; };
struct V3 { float x, y, z; };

__device__ __forceinline__ void wave_fence_lgkm() {
    asm volatile("s_waitcnt lgkmcnt(0)" ::: "memory");
    __builtin_amdgcn_wave_barrier();
}

__device__ __forceinline__ M3 rot6d(const float* r) {
    float x0 = r[0], x1 = r[1], x2 = r[2];
    float y0 = r[3], y1 = r[4], y2 = r[5];
    float inx = rsqrtf(fmaxf(x0*x0 + x1*x1 + x2*x2, 1e-16f));
    x0 *= inx; x1 *= inx; x2 *= inx;
    float z0 = x1*y2 - x2*y1;
    float z1 = x2*y0 - x0*y2;
    float z2 = x0*y1 - x1*y0;
    float inz = rsqrtf(fmaxf(z0*z0 + z1*z1 + z2*z2, 1e-16f));
    z0 *= inz; z1 *= inz; z2 *= inz;
    float w0 = z1*x2 - z2*x1;
    float w1 = z2*x0 - z0*x2;
    float w2 = z0*x1 - z1*x0;
    M3 R;
    R.a[0] = x0; R.a[1] = w0; R.a[2] = z0;
    R.a[3] = x1; R.a[4] = w1; R.a[5] = z1;
    R.a[6] = x2; R.a[7] = w2; R.a[8] = z2;
    return R;
}

__device__ __forceinline__ M3 m3mul(const M3& A, const M3& B) {
    M3 C;
#pragma unroll
    for (int r = 0; r < 3; ++r)
#pragma unroll
        for (int c = 0; c < 3; ++c)
            C.a[3*r + c] = A.a[3*r + 0] * B.a[0 + c]
                         + A.a[3*r + 1] * B.a[3 + c]
                         + A.a[3*r + 2] * B.a[6 + c];
    return C;
}

__device__ __forceinline__ V3 step(const M3& P, V3 pp, int axis, float s) {
    V3 q;
    q.x = pp.x + s * P.a[0 + axis];
    q.y = pp.y + s * P.a[3 + axis];
    q.z = pp.z + s * P.a[6 + axis];
    return q;
}

__global__ __launch_bounds__(TPB) void PoseDecoder_kernel(
    const float* __restrict__ rot,    // [BL,17,6]
    const float* __restrict__ bones,  // [B,16]
    const float* __restrict__ root,   // [BL,3]
    float* __restrict__ out,          // [BL,17,3]
    int BL, int L)
{
    __shared__ __align__(16) float s_buf[TPB * STRIDE_IN];  // 26112 B
    const int t = threadIdx.x;
    const int base = blockIdx.x * TPB;
    const bool full = (base + TPB <= BL);       // always true when BL % 64 == 0

    // ---- Phase 1: global -> LDS via DMA (all transactions in flight at once) ----
    if (full) {
        const char* gb = (const char*)rot + (size_t)base * 408;
#pragma unroll
        for (int r = 0; r < 25; ++r) {
            __builtin_amdgcn_global_load_lds(
                (g_void*)(gb + r * 1024 + t * 16),
                (lds_void*)(s_buf + r * 256),
                16, 0, 0);
        }
        // tail 512 B = two 4-byte-per-lane rounds
        __builtin_amdgcn_global_load_lds((g_void*)(gb + 25600 + t * 4),
                                         (lds_void*)(s_buf + 6400), 4, 0, 0);
        __builtin_amdgcn_global_load_lds((g_void*)(gb + 25856 + t * 4),
                                         (lds_void*)(s_buf + 6464), 4, 0, 0);
    } else {
        const int nf = (BL - base) * 102;
        for (int e = t; e < nf; e += TPB) s_buf[e] = rot[(size_t)base * 102 + e];
    }

    // root loads issued before the wait — they ride the same latency window
    const int gs = base + t;
    const bool lane_ok = gs < BL;
    float rx = 0.f, ry = 0.f, rz = 0.f;
    if (lane_ok) {
        rx = root[3 * (size_t)gs + 0];
        ry = root[3 * (size_t)gs + 1];
        rz = root[3 * (size_t)gs + 2];
    }

    // bone lengths: wave-uniform scalar loads on the fast path
    float len[16];
    if (full && (base / L == (base + TPB - 1) / L)) {
        const float* bl = bones + (size_t)(base / L) * 16;
#pragma unroll
        for (int k = 0; k < 16; ++k) len[k] = bl[k];
    } else if (lane_ok) {
        const float* bl = bones + (size_t)(gs / L) * 16;
#pragma unroll
        for (int k = 0; k < 16; ++k) len[k] = bl[k];
    } else {
#pragma unroll
        for (int k = 0; k < 16; ++k) len[k] = 0.f;
    }

    // drain DMA + root loads (+ fallback ds_writes)
    asm volatile("s_waitcnt vmcnt(0) lgkmcnt(0)" ::: "memory");
    __builtin_amdgcn_wave_barrier();

    // ---- Phase 2: per-lane FK out of LDS ----
    float res[51];
    if (lane_ok) {
        const float* r6 = s_buf + t * STRIDE_IN;

        V3 q0; q0.x = rx; q0.y = ry; q0.z = rz;
        M3 W0 = rot6d(r6 + 0);
        res[0] = q0.x; res[1] = q0.y; res[2] = q0.z;

        // chain 0 -> 1 -> 2 -> 3
        M3 W1 = m3mul(W0, rot6d(r6 + 1*6));  V3 q1 = step(W0, q0, 0, -len[0]);
        M3 W2 = m3mul(W1, rot6d(r6 + 2*6));  V3 q2 = step(W1, q1, 1, -len[1]);
        /* leaf 3 */                         V3 q3 = step(W2, q2, 1, -len[2]);
        res[3]=q1.x; res[4]=q1.y; res[5]=q1.z;
        res[6]=q2.x; res[7]=q2.y; res[8]=q2.z;
        res[9]=q3.x; res[10]=q3.y; res[11]=q3.z;

        // chain 0 -> 4 -> 5 -> 6
        M3 W4 = m3mul(W0, rot6d(r6 + 4*6));  V3 q4 = step(W0, q0, 0,  len[3]);
        M3 W5 = m3mul(W4, rot6d(r6 + 5*6));  V3 q5 = step(W4, q4, 1, -len[4]);
        /* leaf 6 */                         V3 q6 = step(W5, q5, 1, -len[5]);
        res[12]=q4.x; res[13]=q4.y; res[14]=q4.z;
        res[15]=q5.x; res[16]=q5.y; res[17]=q5.z;
        res[18]=q6.x; res[19]=q6.y; res[20]=q6.z;

        // chain 0 -> 7 -> 8
        M3 W7 = m3mul(W0, rot6d(r6 + 7*6));  V3 q7 = step(W0, q0, 1,  len[6]);
        M3 W8 = m3mul(W7, rot6d(r6 + 8*6));  V3 q8 = step(W7, q7, 1,  len[7]);
        res[21]=q7.x; res[22]=q7.y; res[23]=q7.z;
        res[24]=q8.x; res[25]=q8.y; res[26]=q8.z;

        // chain 8 -> 9 -> 10
        M3 W9 = m3mul(W8, rot6d(r6 + 9*6));  V3 q9 = step(W8, q8, 1,  len[8]);
        /* leaf 10 */                        V3 q10 = step(W9, q9, 1, len[9]);
        res[27]=q9.x; res[28]=q9.y; res[29]=q9.z;
        res[30]=q10.x; res[31]=q10.y; res[32]=q10.z;

        // chain 8 -> 11 -> 12 -> 13
        M3 W11 = m3mul(W8,  rot6d(r6 + 11*6)); V3 q11 = step(W8,  q8,  0, len[10]);
        M3 W12 = m3mul(W11, rot6d(r6 + 12*6)); V3 q12 = step(W11, q11, 0, len[11]);
        /* leaf 13 */                          V3 q13 = step(W12, q12, 0, len[12]);
        res[33]=q11.x; res[34]=q11.y; res[35]=q11.z;
        res[36]=q12.x; res[37]=q12.y; res[38]=q12.z;
        res[39]=q13.x; res[40]=q13.y; res[41]=q13.z;

        // chain 8 -> 14 -> 15 -> 16
        M3 W14 = m3mul(W8,  rot6d(r6 + 14*6)); V3 q14 = step(W8,  q8,  0, -len[13]);
        M3 W15 = m3mul(W14, rot6d(r6 + 15*6)); V3 q15 = step(W14, q14, 0, -len[14]);
        /* leaf 16 */                          V3 q16 = step(W15, q15, 0, -len[15]);
        res[42]=q14.x; res[43]=q14.y; res[44]=q14.z;
        res[45]=q15.x; res[46]=q15.y; res[47]=q15.z;
        res[48]=q16.x; res[49]=q16.y; res[50]=q16.z;
    }
    wave_fence_lgkm();   // all input LDS reads retired before the overlay write

    // ---- Phase 3: results -> LDS overlay (stride 51, 2-way banks = free) ----
    if (lane_ok) {
        float* so = s_buf + t * 51;
#pragma unroll
        for (int m = 0; m < 51; ++m) so[m] = res[m];
    }
    wave_fence_lgkm();

    // ---- Phase 4: coalesced LDS -> global (float4, compile-time bounds) ----
    if (full) {
        float4* o4 = (float4*)(out + (size_t)base * 51);
        const float4* l4 = (const float4*)s_buf;
#pragma unroll
        for (int r = 0; r < 12; ++r) o4[r * 64 + t] = l4[r * 64 + t];
        if (t < 48) o4[768 + t] = l4[768 + t];
    } else {
        const int nf = (BL - base) * 51;
        for (int e = t; e < nf; e += TPB)
            out[(size_t)base * 51 + e] = s_buf[e];
    }
}

extern "C" void kernel_launch(void* const* d_in, const int* in_sizes, int n_in,
                              void* d_out, int out_size, void* d_ws, size_t ws_size,
                              hipStream_t stream) {
    const float* rot   = (const float*)d_in[0];
    const float* bones = (const float*)d_in[1];
    const float* root  = (const float*)d_in[2];
    float* out = (float*)d_out;

    int BL = in_sizes[0] / 102;     // 17 joints * 6
    int B  = in_sizes[1] / 16;      // 16 bones
    int L  = BL / B;

    int grid = (BL + TPB - 1) / TPB;
    PoseDecoder_kernel<<<grid, TPB, 0, stream>>>(rot, bones, root, out, BL, L);
}